// Round 10
// baseline (658.963 us; speedup 1.0000x reference)
//
#include <hip/hip_runtime.h>
#include <hip/hip_cooperative_groups.h>
#include <math.h>

namespace cg = cooperative_groups;

typedef unsigned char  uchar_t;
typedef unsigned int   uint32;
typedef __attribute__((ext_vector_type(4)))  int   i32x4;
typedef __attribute__((ext_vector_type(8)))  int   i32x8;
typedef __attribute__((ext_vector_type(16))) float f32x16;

#define EMB     512
#define NROWS   8192
#define NITEMS  4096
#define NSPLIT  8
#define CPS     1024
#define CTILE   256
#define QTILE   128
#define NSTEPS  32
#define LDEPTH  12
#define KEEP    16
#define NRESC   16
#define NJOBS   512      // (NROWS/QTILE)*NSPLIT sim jobs

#define GLOAD_LDS(gp, lp) __builtin_amdgcn_global_load_lds( \
    (const __attribute__((address_space(1))) void*)(gp),    \
    (__attribute__((address_space(3))) void*)(lp), 16, 0, 0)

__device__ inline uint32 packkey(float v, int idx) {
    uint32 u = __float_as_uint(v);
    uint32 s = u ^ ((u & 0x80000000u) ? 0xFFFFFFFFu : 0x80000000u);
    return (s & 0xFFFFE000u) | ((uint32)idx ^ 0x1FFFu);
}

// ======================= shared phase bodies =======================

union SimShared {
    struct { uchar_t A[2][16384]; uchar_t B[2][8192]; } s;   // 48 KB staging
    struct { uint32 mk[128][65]; } m;                         // 33.3 KB merge
    struct { uint32 skeys[128]; float4 sq[128];
             int scand[NRESC]; double sd[NRESC]; int sci[NRESC];
             float smemb[NRESC]; double contrib[8]; } r;      // rescue scratch
};

__device__ __forceinline__ void prep_rows(const float* __restrict__ E,
                                          uchar_t* __restrict__ Xq,
                                          double* __restrict__ invd,
                                          int base16, int wave, int lane) {
#pragma unroll 1
    for (int i = 0; i < 4; ++i) {
        const int row = base16 + wave * 4 + i;
        const float4* p = (const float4*)(E + (size_t)row * EMB);
        float4 f0 = p[lane];
        float4 f1 = p[lane + 64];
        double s = (double)f0.x*f0.x + (double)f0.y*f0.y + (double)f0.z*f0.z + (double)f0.w*f0.w
                 + (double)f1.x*f1.x + (double)f1.y*f1.y + (double)f1.z*f1.z + (double)f1.w*f1.w;
#pragma unroll
        for (int m = 32; m > 0; m >>= 1) s += __shfl_xor(s, m);
        const double inv = 1.0 / sqrt(s);
        if (lane == 0) invd[row] = inv;
        const float sc = (float)inv * 16.0f;
        int w0 = 0, w1 = 0;
        w0 = __builtin_amdgcn_cvt_pk_fp8_f32(f0.x * sc, f0.y * sc, w0, false);
        w0 = __builtin_amdgcn_cvt_pk_fp8_f32(f0.z * sc, f0.w * sc, w0, true);
        w1 = __builtin_amdgcn_cvt_pk_fp8_f32(f1.x * sc, f1.y * sc, w1, false);
        w1 = __builtin_amdgcn_cvt_pk_fp8_f32(f1.z * sc, f1.w * sc, w1, true);
        ((int2*)(Xq + (size_t)row * EMB))[lane] = make_int2(w0, w1);
    }
}

// one sim job: (qbase, split) -> keys[qbase.., split]
__device__ __forceinline__ void sim_job(SimShared& sh,
                                        const uchar_t* __restrict__ Xq,
                                        uint32* __restrict__ keys,
                                        int qbase, int split,
                                        int t, int lane, int wave,
                                        const int* laneglob, const int* ldsoff,
                                        const bool* isAf) {
    const int wm  = wave >> 1;
    const int wn  = wave & 1;
    const int l31 = lane & 31;
    const int l5  = lane >> 5;

    auto stage = [&](int cand0, int kslab, int buf) {
#pragma unroll
        for (int c = 0; c < 6; ++c) {
            const size_t goff = (size_t)(isAf[c] ? cand0 : qbase) * EMB + kslab + laneglob[c];
            uchar_t* lp = (isAf[c] ? sh.s.A[buf] : sh.s.B[buf]) + ldsoff[c];
            GLOAD_LDS(Xq + goff, lp);
        }
    };

    uint32 tv[2][LDEPTH];
#pragma unroll
    for (int fc = 0; fc < 2; ++fc)
#pragma unroll
        for (int s = 0; s < LDEPTH; ++s) tv[fc][s] = 0u;

    f32x16 acc[4][2];
#pragma unroll
    for (int fr = 0; fr < 4; ++fr)
#pragma unroll
        for (int fc = 0; fc < 2; ++fc)
#pragma unroll
            for (int q = 0; q < 16; ++q) acc[fr][fc][q] = 0.f;

    stage(split * CPS, 0, 0);

    const int fo = (l5 << 10) + (l31 << 4);

#pragma unroll 1
    for (int s = 0; s < NSTEPS; ++s) {
        const int buf   = s & 1;
        const int cand0 = split * CPS + (s >> 3) * CTILE;

        __syncthreads();

        if (s + 1 < NSTEPS) {
            const int s2 = s + 1;
            stage(split * CPS + (s2 >> 3) * CTILE, (s2 & 7) * 64, s2 & 1);
        }

        i32x8 af[4], bf[2];
#pragma unroll
        for (int fr = 0; fr < 4; ++fr) {
            const int ca = (wm * 4 + fr) * 2048;
            i32x4 lo = *(const i32x4*)&sh.s.A[buf][ca + fo];
            i32x4 hi = *(const i32x4*)&sh.s.A[buf][ca + 512 + fo];
            i32x8 v;
            v[0] = lo[0]; v[1] = lo[1]; v[2] = lo[2]; v[3] = lo[3];
            v[4] = hi[0]; v[5] = hi[1]; v[6] = hi[2]; v[7] = hi[3];
            af[fr] = v;
        }
#pragma unroll
        for (int fc = 0; fc < 2; ++fc) {
            const int cb = (wn * 2 + fc) * 2048;
            i32x4 lo = *(const i32x4*)&sh.s.B[buf][cb + fo];
            i32x4 hi = *(const i32x4*)&sh.s.B[buf][cb + 512 + fo];
            i32x8 v;
            v[0] = lo[0]; v[1] = lo[1]; v[2] = lo[2]; v[3] = lo[3];
            v[4] = hi[0]; v[5] = hi[1]; v[6] = hi[2]; v[7] = hi[3];
            bf[fc] = v;
        }

#pragma unroll
        for (int fr = 0; fr < 4; ++fr)
#pragma unroll
            for (int fc = 0; fc < 2; ++fc)
                acc[fr][fc] = __builtin_amdgcn_mfma_scale_f32_32x32x64_f8f6f4(
                    af[fr], bf[fc], acc[fr][fc],
                    0, 0, 0, 0x7F7F7F7F, 0, 0x7F7F7F7F);

        if ((s & 7) == 7) {
#pragma unroll
            for (int fc = 0; fc < 2; ++fc) {
#pragma unroll
                for (int fr = 0; fr < 4; ++fr) {
                    float m0 = fmaxf(fmaxf(acc[fr][fc][0],  acc[fr][fc][1]),  fmaxf(acc[fr][fc][2],  acc[fr][fc][3]));
                    float m1 = fmaxf(fmaxf(acc[fr][fc][4],  acc[fr][fc][5]),  fmaxf(acc[fr][fc][6],  acc[fr][fc][7]));
                    float m2 = fmaxf(fmaxf(acc[fr][fc][8],  acc[fr][fc][9]),  fmaxf(acc[fr][fc][10], acc[fr][fc][11]));
                    float m3 = fmaxf(fmaxf(acc[fr][fc][12], acc[fr][fc][13]), fmaxf(acc[fr][fc][14], acc[fr][fc][15]));
                    float mx = fmaxf(fmaxf(m0, m1), fmaxf(m2, m3));
                    if (packkey(mx, 0) > tv[fc][LDEPTH - 1]) {
                        const int jb = cand0 + wm * 128 + fr * 32 + (l5 << 2);
#pragma unroll
                        for (int reg = 0; reg < 16; ++reg) {
                            const int ci = jb + (reg & 3) + ((reg >> 2) << 3);
                            uint32 key = packkey(acc[fr][fc][reg], ci);
                            if (key > tv[fc][LDEPTH - 1]) {
                                uint32 cur = key;
#pragma unroll
                                for (int d = 0; d < LDEPTH; ++d) {
                                    uint32 a  = tv[fc][d];
                                    bool   gt = cur > a;
                                    tv[fc][d] = gt ? cur : a;
                                    cur       = gt ? a : cur;
                                }
                            }
                        }
                    }
#pragma unroll
                    for (int q = 0; q < 16; ++q) acc[fr][fc][q] = 0.f;
                }
            }
        }
    }

    __syncthreads();
#pragma unroll
    for (int fc = 0; fc < 2; ++fc) {
        const int col = wn * 64 + fc * 32 + l31;
        const int sl  = wm * 2 + l5;
#pragma unroll
        for (int d = 0; d < LDEPTH; ++d) sh.m.mk[col][sl * 16 + d] = tv[fc][d];
#pragma unroll
        for (int d = LDEPTH; d < 16; ++d) sh.m.mk[col][sl * 16 + d] = 0u;
    }
    __syncthreads();
    if (t < 128) {
        int p[4] = {0, 0, 0, 0};
        const size_t base = ((size_t)(qbase + t) * NSPLIT + split) * KEEP;
#pragma unroll 1
        for (int sel = 0; sel < KEEP; ++sel) {
            uint32 bk = 0; int bl = 0;
#pragma unroll
            for (int l = 0; l < 4; ++l) {
                uint32 k = sh.m.mk[t][l * 16 + p[l]];
                if (k > bk) { bk = k; bl = l; }
            }
            p[bl]++;
            keys[base + sel] = bk;
        }
    }
}

__device__ __forceinline__ void rescue_row(SimShared& sh,
                                           const float* __restrict__ E,
                                           const double* __restrict__ invd,
                                           const uint32* __restrict__ keys,
                                           const int* __restrict__ n_users,
                                           const int* __restrict__ n_entitys,
                                           const int* __restrict__ interactions,
                                           float* __restrict__ out,
                                           int row, int t) {
    if (t < 128) {
        sh.r.skeys[t] = keys[(size_t)row * 128 + t];
        sh.r.sq[t]    = ((const float4*)(E + (size_t)row * EMB))[t];
    }
    if (t < NRESC) sh.r.scand[t] = 0;
    if (t < 8)     sh.r.contrib[t] = 0.0;
    __syncthreads();

    if (t < 128) {
        const uint32 k = sh.r.skeys[t];
        int r = 0;
#pragma unroll 16
        for (int j = 0; j < 128; ++j) {
            const uint32 kj = sh.r.skeys[j];
            r += (kj > k) || (kj == k && j < t);
        }
        if (r < NRESC) sh.r.scand[r] = (int)((k & 0x1FFFu) ^ 0x1FFFu);
    }
    __syncthreads();

    const int g    = t >> 4;
    const int l16  = t & 15;
    const int cand = sh.r.scand[g] & (NROWS - 1);
    const float4* C = (const float4*)(E + (size_t)cand * EMB);
    double acc = 0.0;
#pragma unroll
    for (int j = 0; j < 8; ++j) {
        float4 c = C[l16 + 16 * j];
        float4 q = sh.r.sq[l16 + 16 * j];
        acc += (double)q.x * c.x + (double)q.y * c.y
             + (double)q.z * c.z + (double)q.w * c.w;
    }
#pragma unroll
    for (int m = 8; m >= 1; m >>= 1) acc += __shfl_xor(acc, m, 16);

    const int ent = n_entitys[row];
    if (l16 == 0) { sh.r.sd[g] = acc * invd[row] * invd[cand]; sh.r.sci[g] = cand; }
    if (l16 == 1) {
        const int uid = n_users[cand];
        sh.r.smemb[g] = (float)interactions[(size_t)uid * NITEMS + ent];
    }
    __syncthreads();

    if (t < NRESC) {
        const double v  = sh.r.sd[t];
        const int    ci = sh.r.sci[t];
        int r = 0;
#pragma unroll
        for (int j = 0; j < NRESC; ++j) {
            const double vj = sh.r.sd[j];
            const int    cj = sh.r.sci[j];
            r += (vj > v) || (vj == v && (cj < ci || (cj == ci && j < t)));
        }
        if (r < 6) sh.r.contrib[r] = v * (double)sh.r.smemb[t];
    }
    __syncthreads();
    if (t == 0) {
        const double sum = sh.r.contrib[0] + sh.r.contrib[1] + sh.r.contrib[2]
                         + sh.r.contrib[3] + sh.r.contrib[4] + sh.r.contrib[5];
        out[row] = (float)(sum * (1.0 / 6.0));
    }
    __syncthreads();   // protect shared reuse
}

// ======================= cooperative mega-kernel (grid-flexible) =======================
__global__ __launch_bounds__(256, 2) void mega_kernel(
    const float* __restrict__ E,
    const int* __restrict__ n_users, const int* __restrict__ n_entitys,
    const int* __restrict__ interactions,
    uchar_t* __restrict__ Xq, double* __restrict__ invd,
    uint32* __restrict__ keys, float* __restrict__ out) {

    __shared__ SimShared sh;

    const int t    = threadIdx.x;
    const int lane = t & 63;
    const int wave = t >> 6;
    const int G    = gridDim.x;

    // phase A: prep, 16 rows per job
#pragma unroll 1
    for (int j = blockIdx.x; j < NROWS / 16; j += G)
        prep_rows(E, Xq, invd, j * 16, wave, lane);
    __threadfence();
    cg::this_grid().sync();

    // phase B: sim jobs
    int  laneglob[6];
    int  ldsoff[6];
    bool isAf[6];
#pragma unroll
    for (int c = 0; c < 6; ++c) {
        const int g2 = wave * 6 + c;
        const bool a = (g2 < 16);
        const int jj = a ? g2 : (g2 - 16);
        const int rowin = (jj >> 1) * 32 + (lane & 31);
        const int kb    = (((jj & 1) << 1) + (lane >> 5)) << 4;
        laneglob[c] = rowin * EMB + kb;
        ldsoff[c]   = jj * 1024;
        isAf[c]     = a;
    }
#pragma unroll 1
    for (int j = blockIdx.x; j < NJOBS; j += G) {
        __syncthreads();   // protect union: prev job's merge reads done
        sim_job(sh, Xq, keys, (j >> 3) * QTILE, j & 7, t, lane, wave,
                laneglob, ldsoff, isAf);
    }
    __threadfence();
    cg::this_grid().sync();

    // phase C: rescue, one row per job
#pragma unroll 1
    for (int row = blockIdx.x; row < NROWS; row += G)
        rescue_row(sh, E, invd, keys, n_users, n_entitys, interactions, out, row, t);
}

// ======================= fallback 3-kernel path (r8-equivalent) =======================
__global__ void prep_kernel(const float* __restrict__ E,
                            uchar_t* __restrict__ Xq, double* __restrict__ invd) {
    prep_rows(E, Xq, invd, blockIdx.x * 16, threadIdx.x >> 6, threadIdx.x & 63);
}

__global__ __launch_bounds__(256, 2) void sim_topk_mfma(
    const uchar_t* __restrict__ Xq, uint32* __restrict__ keys) {
    __shared__ SimShared sh;
    const int t    = threadIdx.x;
    const int lane = t & 63;
    const int wave = t >> 6;
    int  laneglob[6];
    int  ldsoff[6];
    bool isAf[6];
#pragma unroll
    for (int c = 0; c < 6; ++c) {
        const int g2 = wave * 6 + c;
        const bool a = (g2 < 16);
        const int jj = a ? g2 : (g2 - 16);
        const int rowin = (jj >> 1) * 32 + (lane & 31);
        const int kb    = (((jj & 1) << 1) + (lane >> 5)) << 4;
        laneglob[c] = rowin * EMB + kb;
        ldsoff[c]   = jj * 1024;
        isAf[c]     = a;
    }
    sim_job(sh, Xq, keys, (blockIdx.x >> 3) * QTILE, blockIdx.x & 7,
            t, lane, wave, laneglob, ldsoff, isAf);
}

__global__ __launch_bounds__(256) void rescue_kernel(
    const float* __restrict__ E, const double* __restrict__ invd,
    const uint32* __restrict__ keys,
    const int* __restrict__ n_users, const int* __restrict__ n_entitys,
    const int* __restrict__ interactions, float* __restrict__ out) {
    __shared__ SimShared sh;
    rescue_row(sh, E, invd, keys, n_users, n_entitys, interactions, out,
               blockIdx.x, threadIdx.x);
}

extern "C" void kernel_launch(void* const* d_in, const int* in_sizes, int n_in,
                              void* d_out, int out_size, void* d_ws, size_t ws_size,
                              hipStream_t stream) {
    const float* E            = (const float*)d_in[0];
    const int*   n_users      = (const int*)d_in[1];
    const int*   n_entitys    = (const int*)d_in[2];
    const int*   interactions = (const int*)d_in[3];
    float*       out          = (float*)d_out;

    uchar_t* Xq   = (uchar_t*)d_ws;
    double*  invd = (double*)(Xq + (size_t)NROWS * EMB);
    uint32*  keys = (uint32*)(invd + NROWS);

    // stateless, deterministic queries (capture-safe, same result every call)
    int coop = 0, dev = 0;
    hipGetDevice(&dev);
    hipDeviceGetAttribute(&coop, hipDeviceAttributeCooperativeLaunch, dev);
    int maxb = 0;
    hipOccupancyMaxActiveBlocksPerMultiprocessor(&maxb, mega_kernel, 256, 0);

    if (coop && maxb >= 1) {
        const int grid = (maxb >= 2) ? NJOBS : 256;
        void* args[] = { (void*)&E, (void*)&n_users, (void*)&n_entitys,
                         (void*)&interactions, (void*)&Xq, (void*)&invd,
                         (void*)&keys, (void*)&out };
        hipError_t err = hipLaunchCooperativeKernel((const void*)mega_kernel,
                                                    dim3(grid), dim3(256),
                                                    args, 0, stream);
        if (err == hipSuccess) return;
    }

    // fallback: known-good 3-kernel pipeline
    prep_kernel<<<NROWS / 16, 256, 0, stream>>>(E, Xq, invd);
    sim_topk_mfma<<<NJOBS, 256, 0, stream>>>(Xq, keys);
    rescue_kernel<<<NROWS, 256, 0, stream>>>(E, invd, keys, n_users, n_entitys,
                                             interactions, out);
}

// Round 11
// 341.096 us; speedup vs baseline: 1.9319x; 1.9319x over previous
//
#include <hip/hip_runtime.h>
#include <math.h>

typedef unsigned char  uchar_t;
typedef unsigned int   uint32;
typedef __attribute__((ext_vector_type(4)))  int   i32x4;
typedef __attribute__((ext_vector_type(8)))  int   i32x8;
typedef __attribute__((ext_vector_type(16))) float f32x16;

#define EMB     512
#define NROWS   8192
#define NITEMS  4096
#define NSPLIT  8
#define CPS     1024
#define CTILE   256
#define QTILE   128
#define NSTEPS  32
#define LDEPTH  8
#define KEEP    16
#define NRESC   16

#define GLOAD_LDS(gp, lp) __builtin_amdgcn_global_load_lds( \
    (const __attribute__((address_space(1))) void*)(gp),    \
    (__attribute__((address_space(3))) void*)(lp), 16, 0, 0)

__device__ inline uint32 packkey(float v, int idx) {
    uint32 u = __float_as_uint(v);
    uint32 s = u ^ ((u & 0x80000000u) ? 0xFFFFFFFFu : 0x80000000u);
    return (s & 0xFFFFE000u) | ((uint32)idx ^ 0x1FFFu);
}

// ---------------- Phase A: fp64 norms + normalized fp8(e4m3, x16) plane ----------------
__global__ void prep_kernel(const float* __restrict__ E,
                            uchar_t* __restrict__ Xq, double* __restrict__ invd) {
    const int row  = blockIdx.x * 4 + (threadIdx.x >> 6);
    const int lane = threadIdx.x & 63;
    const float4* p = (const float4*)(E + (size_t)row * EMB);
    float4 f0 = p[lane];
    float4 f1 = p[lane + 64];
    double s = (double)f0.x*f0.x + (double)f0.y*f0.y + (double)f0.z*f0.z + (double)f0.w*f0.w
             + (double)f1.x*f1.x + (double)f1.y*f1.y + (double)f1.z*f1.z + (double)f1.w*f1.w;
#pragma unroll
    for (int m = 32; m > 0; m >>= 1) s += __shfl_xor(s, m);
    const double inv = 1.0 / sqrt(s);
    if (lane == 0) invd[row] = inv;
    const float sc = (float)inv * 16.0f;
    int w0 = 0, w1 = 0;
    w0 = __builtin_amdgcn_cvt_pk_fp8_f32(f0.x * sc, f0.y * sc, w0, false);
    w0 = __builtin_amdgcn_cvt_pk_fp8_f32(f0.z * sc, f0.w * sc, w0, true);
    w1 = __builtin_amdgcn_cvt_pk_fp8_f32(f1.x * sc, f1.y * sc, w1, false);
    w1 = __builtin_amdgcn_cvt_pk_fp8_f32(f1.z * sc, f1.w * sc, w1, true);
    ((int2*)(Xq + (size_t)row * EMB))[lane] = make_int2(w0, w1);
}

// ---------------- Phase B: dbuf MX-fp8 32x32x64 MFMA, 256x128 tile (r8 codegen) ----------------
__global__ __launch_bounds__(256, 2) void sim_topk_mfma(
    const uchar_t* __restrict__ Xq, uint32* __restrict__ keys_out) {

    __shared__ union {
        struct { uchar_t A[2][16384]; uchar_t B[2][8192]; } s;  // 48 KB dbuf staging
        struct { uint32 mk[128][65]; } m;                        // 33.3 KB merge
    } sh;

    const int t     = threadIdx.x;
    const int lane  = t & 63;
    const int wave  = t >> 6;
    const int wm    = wave >> 1;
    const int wn    = wave & 1;
    const int rb    = blockIdx.x >> 3;
    const int split = blockIdx.x & 7;
    const int qbase = rb * QTILE;
    const int l31   = lane & 31;
    const int l5    = lane >> 5;

    // 24 DMAs/step (A:16, B:8) -> 6 per wave; descriptors as LOCALS (keep r8 codegen)
    int  laneglob[6];
    int  ldsoff[6];
    bool isAf[6];
#pragma unroll
    for (int c = 0; c < 6; ++c) {
        const int G = wave * 6 + c;
        const bool a = (G < 16);
        const int j = a ? G : (G - 16);
        const int rowin = (j >> 1) * 32 + l31;
        const int kb    = (((j & 1) << 1) + l5) << 4;
        laneglob[c] = rowin * EMB + kb;
        ldsoff[c]   = j * 1024;
        isAf[c]     = a;
    }

    auto stage = [&](int cand0, int kslab, int buf) {
#pragma unroll
        for (int c = 0; c < 6; ++c) {
            const size_t goff = (size_t)(isAf[c] ? cand0 : qbase) * EMB + kslab + laneglob[c];
            uchar_t* lp = (isAf[c] ? sh.s.A[buf] : sh.s.B[buf]) + ldsoff[c];
            GLOAD_LDS(Xq + goff, lp);
        }
    };

    uint32 tv[2][LDEPTH];
#pragma unroll
    for (int fc = 0; fc < 2; ++fc)
#pragma unroll
        for (int s = 0; s < LDEPTH; ++s) tv[fc][s] = 0u;

    f32x16 acc[4][2];
#pragma unroll
    for (int fr = 0; fr < 4; ++fr)
#pragma unroll
        for (int fc = 0; fc < 2; ++fc)
#pragma unroll
            for (int q = 0; q < 16; ++q) acc[fr][fc][q] = 0.f;

    stage(split * CPS, 0, 0);

    const int fo = (l5 << 10) + (l31 << 4);

#pragma unroll 1
    for (int s = 0; s < NSTEPS; ++s) {
        const int buf   = s & 1;
        const int cand0 = split * CPS + (s >> 3) * CTILE;

        __syncthreads();

        if (s + 1 < NSTEPS) {
            const int s2 = s + 1;
            stage(split * CPS + (s2 >> 3) * CTILE, (s2 & 7) * 64, s2 & 1);
        }

        i32x8 af[4], bf[2];
#pragma unroll
        for (int fr = 0; fr < 4; ++fr) {
            const int ca = (wm * 4 + fr) * 2048;
            i32x4 lo = *(const i32x4*)&sh.s.A[buf][ca + fo];
            i32x4 hi = *(const i32x4*)&sh.s.A[buf][ca + 512 + fo];
            i32x8 v;
            v[0] = lo[0]; v[1] = lo[1]; v[2] = lo[2]; v[3] = lo[3];
            v[4] = hi[0]; v[5] = hi[1]; v[6] = hi[2]; v[7] = hi[3];
            af[fr] = v;
        }
#pragma unroll
        for (int fc = 0; fc < 2; ++fc) {
            const int cb = (wn * 2 + fc) * 2048;
            i32x4 lo = *(const i32x4*)&sh.s.B[buf][cb + fo];
            i32x4 hi = *(const i32x4*)&sh.s.B[buf][cb + 512 + fo];
            i32x8 v;
            v[0] = lo[0]; v[1] = lo[1]; v[2] = lo[2]; v[3] = lo[3];
            v[4] = hi[0]; v[5] = hi[1]; v[6] = hi[2]; v[7] = hi[3];
            bf[fc] = v;
        }

#pragma unroll
        for (int fr = 0; fr < 4; ++fr)
#pragma unroll
            for (int fc = 0; fc < 2; ++fc)
                acc[fr][fc] = __builtin_amdgcn_mfma_scale_f32_32x32x64_f8f6f4(
                    af[fr], bf[fc], acc[fr][fc],
                    0, 0, 0, 0x7F7F7F7F, 0, 0x7F7F7F7F);

        if ((s & 7) == 7) {
#pragma unroll
            for (int fc = 0; fc < 2; ++fc) {
#pragma unroll
                for (int fr = 0; fr < 4; ++fr) {
                    float m0 = fmaxf(fmaxf(acc[fr][fc][0],  acc[fr][fc][1]),  fmaxf(acc[fr][fc][2],  acc[fr][fc][3]));
                    float m1 = fmaxf(fmaxf(acc[fr][fc][4],  acc[fr][fc][5]),  fmaxf(acc[fr][fc][6],  acc[fr][fc][7]));
                    float m2 = fmaxf(fmaxf(acc[fr][fc][8],  acc[fr][fc][9]),  fmaxf(acc[fr][fc][10], acc[fr][fc][11]));
                    float m3 = fmaxf(fmaxf(acc[fr][fc][12], acc[fr][fc][13]), fmaxf(acc[fr][fc][14], acc[fr][fc][15]));
                    float mx = fmaxf(fmaxf(m0, m1), fmaxf(m2, m3));
                    if (packkey(mx, 0) > tv[fc][LDEPTH - 1]) {
                        const int jb = cand0 + wm * 128 + fr * 32 + (l5 << 2);
#pragma unroll
                        for (int reg = 0; reg < 16; ++reg) {
                            const int ci = jb + (reg & 3) + ((reg >> 2) << 3);
                            uint32 key = packkey(acc[fr][fc][reg], ci);
                            if (key > tv[fc][LDEPTH - 1]) {
                                uint32 cur = key;
#pragma unroll
                                for (int d = 0; d < LDEPTH; ++d) {
                                    uint32 a  = tv[fc][d];
                                    bool   gt = cur > a;
                                    tv[fc][d] = gt ? cur : a;
                                    cur       = gt ? a : cur;
                                }
                            }
                        }
                    }
#pragma unroll
                    for (int q = 0; q < 16; ++q) acc[fr][fc][q] = 0.f;
                }
            }
        }
    }

    // ---- merge 4 lane-lists per query, emit sorted top-16 keys ----
    __syncthreads();
#pragma unroll
    for (int fc = 0; fc < 2; ++fc) {
        const int col = wn * 64 + fc * 32 + l31;
        const int sl  = wm * 2 + l5;
#pragma unroll
        for (int d = 0; d < LDEPTH; ++d) sh.m.mk[col][sl * 16 + d] = tv[fc][d];
#pragma unroll
        for (int d = LDEPTH; d < 16; ++d) sh.m.mk[col][sl * 16 + d] = 0u;
    }
    __syncthreads();
    if (t < 128) {
        int p[4] = {0, 0, 0, 0};
        const size_t base = ((size_t)(qbase + t) * NSPLIT + split) * KEEP;
#pragma unroll 1
        for (int sel = 0; sel < KEEP; ++sel) {
            uint32 bk = 0; int bl = 0;
#pragma unroll
            for (int l = 0; l < 4; ++l) {
                uint32 k = sh.m.mk[t][l * 16 + p[l]];
                if (k > bk) { bk = k; bl = l; }
            }
            p[bl]++;
            keys_out[base + sel] = bk;
        }
    }
}

// ---------------- Phase C: one row per block — rank-select top-16 + fp64 rescue ----------------
__global__ __launch_bounds__(256) void rescue_kernel(
    const float* __restrict__ E, const double* __restrict__ invd,
    const uint32* __restrict__ keys,
    const int* __restrict__ n_users, const int* __restrict__ n_entitys,
    const int* __restrict__ interactions, float* __restrict__ out) {

    __shared__ uint32 skeys[128];
    __shared__ float4 sq[128];
    __shared__ int    scand[NRESC];
    __shared__ double sd[NRESC];
    __shared__ int    sci[NRESC];
    __shared__ float  smemb[NRESC];
    __shared__ double contrib[8];

    const int t   = threadIdx.x;
    const int row = blockIdx.x;

    if (t < 128) {
        skeys[t] = keys[(size_t)row * 128 + t];
        sq[t]    = ((const float4*)(E + (size_t)row * EMB))[t];
    }
    if (t < NRESC) scand[t] = 0;      // poison-proof
    if (t < 8)     contrib[t] = 0.0;
    __syncthreads();

    if (t < 128) {
        const uint32 k = skeys[t];
        int r = 0;
#pragma unroll 16
        for (int j = 0; j < 128; ++j) {
            const uint32 kj = skeys[j];
            r += (kj > k) || (kj == k && j < t);
        }
        if (r < NRESC) scand[r] = (int)((k & 0x1FFFu) ^ 0x1FFFu);
    }
    __syncthreads();

    const int g    = t >> 4;
    const int l16  = t & 15;
    const int cand = scand[g] & (NROWS - 1);
    const float4* C = (const float4*)(E + (size_t)cand * EMB);
    double acc = 0.0;
#pragma unroll
    for (int j = 0; j < 8; ++j) {
        float4 c = C[l16 + 16 * j];
        float4 q = sq[l16 + 16 * j];
        acc += (double)q.x * c.x + (double)q.y * c.y
             + (double)q.z * c.z + (double)q.w * c.w;
    }
#pragma unroll
    for (int m = 8; m >= 1; m >>= 1) acc += __shfl_xor(acc, m, 16);

    const int ent = n_entitys[row];
    if (l16 == 0) { sd[g] = acc * invd[row] * invd[cand]; sci[g] = cand; }
    if (l16 == 1) {
        const int uid = n_users[cand];
        smemb[g] = (float)interactions[(size_t)uid * NITEMS + ent];
    }
    __syncthreads();

    if (t < NRESC) {
        const double v  = sd[t];
        const int    ci = sci[t];
        int r = 0;
#pragma unroll
        for (int j = 0; j < NRESC; ++j) {
            const double vj = sd[j];
            const int    cj = sci[j];
            r += (vj > v) || (vj == v && (cj < ci || (cj == ci && j < t)));
        }
        if (r < 6) contrib[r] = v * (double)smemb[t];
    }
    __syncthreads();
    if (t == 0) {
        const double sum = contrib[0] + contrib[1] + contrib[2]
                         + contrib[3] + contrib[4] + contrib[5];
        out[row] = (float)(sum * (1.0 / 6.0));
    }
}

extern "C" void kernel_launch(void* const* d_in, const int* in_sizes, int n_in,
                              void* d_out, int out_size, void* d_ws, size_t ws_size,
                              hipStream_t stream) {
    const float* E            = (const float*)d_in[0];
    const int*   n_users      = (const int*)d_in[1];
    const int*   n_entitys    = (const int*)d_in[2];
    const int*   interactions = (const int*)d_in[3];
    float*       out          = (float*)d_out;

    uchar_t* Xq   = (uchar_t*)d_ws;
    double*  invd = (double*)(Xq + (size_t)NROWS * EMB);
    uint32*  keys = (uint32*)(invd + NROWS);

    prep_kernel<<<NROWS / 4, 256, 0, stream>>>(E, Xq, invd);
    sim_topk_mfma<<<(NROWS / QTILE) * NSPLIT, 256, 0, stream>>>(Xq, keys);
    rescue_kernel<<<NROWS, 256, 0, stream>>>(E, invd, keys, n_users, n_entitys,
                                             interactions, out);
}

// Round 12
// 341.003 us; speedup vs baseline: 1.9324x; 1.0003x over previous
//
#include <hip/hip_runtime.h>
#include <math.h>

typedef unsigned char  uchar_t;
typedef unsigned int   uint32;
typedef __attribute__((ext_vector_type(4)))  int   i32x4;
typedef __attribute__((ext_vector_type(8)))  int   i32x8;
typedef __attribute__((ext_vector_type(16))) float f32x16;

#define EMB     512
#define NROWS   8192
#define NITEMS  4096
#define NSPLIT  8
#define CPS     1024
#define CTILE   256
#define QTILE   128
#define NSTEPS  32
#define LDEPTH  8
#define KEEP    16
#define NRESC   16

#define GLOAD_LDS(gp, lp) __builtin_amdgcn_global_load_lds( \
    (const __attribute__((address_space(1))) void*)(gp),    \
    (__attribute__((address_space(3))) void*)(lp), 16, 0, 0)

__device__ inline uint32 packkey(float v, int idx) {
    uint32 u = __float_as_uint(v);
    uint32 s = u ^ ((u & 0x80000000u) ? 0xFFFFFFFFu : 0x80000000u);
    return (s & 0xFFFFE000u) | ((uint32)idx ^ 0x1FFFu);
}

// ---------------- Phase A: fp64 norms + normalized fp8(e4m3, x16) plane ----------------
__global__ void prep_kernel(const float* __restrict__ E,
                            uchar_t* __restrict__ Xq, double* __restrict__ invd) {
    const int row  = blockIdx.x * 4 + (threadIdx.x >> 6);
    const int lane = threadIdx.x & 63;
    const float4* p = (const float4*)(E + (size_t)row * EMB);
    float4 f0 = p[lane];
    float4 f1 = p[lane + 64];
    double s = (double)f0.x*f0.x + (double)f0.y*f0.y + (double)f0.z*f0.z + (double)f0.w*f0.w
             + (double)f1.x*f1.x + (double)f1.y*f1.y + (double)f1.z*f1.z + (double)f1.w*f1.w;
#pragma unroll
    for (int m = 32; m > 0; m >>= 1) s += __shfl_xor(s, m);
    const double inv = 1.0 / sqrt(s);
    if (lane == 0) invd[row] = inv;
    const float sc = (float)inv * 16.0f;
    int w0 = 0, w1 = 0;
    w0 = __builtin_amdgcn_cvt_pk_fp8_f32(f0.x * sc, f0.y * sc, w0, false);
    w0 = __builtin_amdgcn_cvt_pk_fp8_f32(f0.z * sc, f0.w * sc, w0, true);
    w1 = __builtin_amdgcn_cvt_pk_fp8_f32(f1.x * sc, f1.y * sc, w1, false);
    w1 = __builtin_amdgcn_cvt_pk_fp8_f32(f1.z * sc, f1.w * sc, w1, true);
    ((int2*)(Xq + (size_t)row * EMB))[lane] = make_int2(w0, w1);
}

// ---------------- Phase B: dbuf MX-fp8 32x32x64 MFMA, 256x128 tile ----------------
__global__ __launch_bounds__(256, 2) void sim_topk_mfma(
    const uchar_t* __restrict__ Xq, uint32* __restrict__ keys_out) {

    __shared__ union {
        struct { uchar_t A[2][16384]; uchar_t B[2][8192]; } s;  // 48 KB dbuf staging
        struct { uint32 mk[128][65]; } m;                        // 33.3 KB merge
    } sh;

    const int t     = threadIdx.x;
    const int lane  = t & 63;
    const int wave  = t >> 6;
    const int wm    = wave >> 1;
    const int wn    = wave & 1;
    const int rb    = blockIdx.x >> 3;
    const int split = blockIdx.x & 7;
    const int qbase = rb * QTILE;
    const int l31   = lane & 31;
    const int l5    = lane >> 5;

    // 24 DMAs/step (A:16, B:8) -> 6 per wave; ADDITIVE pointers (no per-step muls)
    const uchar_t* cur[6];
    int  ldsoff[6];
    bool isAf[6];
#pragma unroll
    for (int c = 0; c < 6; ++c) {
        const int G = wave * 6 + c;
        const bool a = (G < 16);
        const int j = a ? G : (G - 16);
        const int rowin = (j >> 1) * 32 + l31;
        const int kb    = (((j & 1) << 1) + l5) << 4;
        isAf[c]   = a;
        ldsoff[c] = j * 1024;
        cur[c]    = Xq + (size_t)((a ? split * CPS : qbase) + rowin) * EMB + kb;
    }
    // per-step increments: within ct +64; at ct boundary A jumps CTILE rows, kslab resets
    const long incA_ct = (long)CTILE * EMB - 7 * 64;   // +130624
    const long incB_ct = -(long)(7 * 64);              // -448

    auto stage = [&](int buf) {
#pragma unroll
        for (int c = 0; c < 6; ++c) {
            uchar_t* lp = (isAf[c] ? sh.s.A[buf] : sh.s.B[buf]) + ldsoff[c];
            GLOAD_LDS(cur[c], lp);
        }
    };

    uint32 tv[2][LDEPTH];
#pragma unroll
    for (int fc = 0; fc < 2; ++fc)
#pragma unroll
        for (int s = 0; s < LDEPTH; ++s) tv[fc][s] = 0u;

    f32x16 acc[4][2];
#pragma unroll
    for (int fr = 0; fr < 4; ++fr)
#pragma unroll
        for (int fc = 0; fc < 2; ++fc)
#pragma unroll
            for (int q = 0; q < 16; ++q) acc[fr][fc][q] = 0.f;

    stage(0);   // prologue: step 0

    const int fo = (l5 << 10) + (l31 << 4);

    union U8 { i32x8 v8; struct { i32x4 lo; i32x4 hi; } h; };

#pragma unroll 1
    for (int s = 0; s < NSTEPS; ++s) {
        const int buf   = s & 1;
        const int cand0 = split * CPS + (s >> 3) * CTILE;

        __syncthreads();   // drains this step's DMA (issued one compute-phase ago)

        if (s + 1 < NSTEPS) {
            const bool newct = ((s + 1) & 7) == 0;
            const long dA = newct ? incA_ct : 64;
            const long dB = newct ? incB_ct : 64;
#pragma unroll
            for (int c = 0; c < 6; ++c) cur[c] += (isAf[c] ? dA : dB);
            stage((s + 1) & 1);
        }

        i32x8 af[4], bf[2];
#pragma unroll
        for (int fr = 0; fr < 4; ++fr) {
            const int ca = (wm * 4 + fr) * 2048;
            U8 u;
            u.h.lo = *(const i32x4*)&sh.s.A[buf][ca + fo];
            u.h.hi = *(const i32x4*)&sh.s.A[buf][ca + 512 + fo];
            af[fr] = u.v8;
        }
#pragma unroll
        for (int fc = 0; fc < 2; ++fc) {
            const int cb = (wn * 2 + fc) * 2048;
            U8 u;
            u.h.lo = *(const i32x4*)&sh.s.B[buf][cb + fo];
            u.h.hi = *(const i32x4*)&sh.s.B[buf][cb + 512 + fo];
            bf[fc] = u.v8;
        }

#pragma unroll
        for (int fr = 0; fr < 4; ++fr)
#pragma unroll
            for (int fc = 0; fc < 2; ++fc)
                acc[fr][fc] = __builtin_amdgcn_mfma_scale_f32_32x32x64_f8f6f4(
                    af[fr], bf[fc], acc[fr][fc],
                    0, 0, 0, 0x7F7F7F7F, 0, 0x7F7F7F7F);

        if ((s & 7) == 7) {
            // ---- register-only epilogue: packed-key insert into per-lane top-8 ----
#pragma unroll
            for (int fc = 0; fc < 2; ++fc) {
#pragma unroll
                for (int fr = 0; fr < 4; ++fr) {
                    // max3-shaped reduction tree (8 ops)
                    float t0 = fmaxf(fmaxf(acc[fr][fc][0],  acc[fr][fc][1]),  acc[fr][fc][2]);
                    float t1 = fmaxf(fmaxf(acc[fr][fc][3],  acc[fr][fc][4]),  acc[fr][fc][5]);
                    float t2 = fmaxf(fmaxf(acc[fr][fc][6],  acc[fr][fc][7]),  acc[fr][fc][8]);
                    float t3 = fmaxf(fmaxf(acc[fr][fc][9],  acc[fr][fc][10]), acc[fr][fc][11]);
                    float t4 = fmaxf(fmaxf(acc[fr][fc][12], acc[fr][fc][13]), acc[fr][fc][14]);
                    float mx = fmaxf(fmaxf(fmaxf(t0, t1), t2),
                                     fmaxf(fmaxf(t3, t4), acc[fr][fc][15]));
                    if (packkey(mx, 0) > tv[fc][LDEPTH - 1]) {
                        const int jb = cand0 + wm * 128 + fr * 32 + (l5 << 2);
#pragma unroll
                        for (int reg = 0; reg < 16; ++reg) {
                            const int ci = jb + (reg & 3) + ((reg >> 2) << 3);
                            uint32 key = packkey(acc[fr][fc][reg], ci);
                            if (key > tv[fc][LDEPTH - 1]) {
                                uint32 cur2 = key;
#pragma unroll
                                for (int d = 0; d < LDEPTH; ++d) {
                                    uint32 a  = tv[fc][d];
                                    bool   gt = cur2 > a;
                                    tv[fc][d] = gt ? cur2 : a;
                                    cur2      = gt ? a : cur2;
                                }
                            }
                        }
                    }
#pragma unroll
                    for (int q = 0; q < 16; ++q) acc[fr][fc][q] = 0.f;
                }
            }
        }
    }

    // ---- merge 4 lane-lists per query, emit sorted top-16 keys ----
    __syncthreads();
#pragma unroll
    for (int fc = 0; fc < 2; ++fc) {
        const int col = wn * 64 + fc * 32 + l31;
        const int sl  = wm * 2 + l5;
#pragma unroll
        for (int d = 0; d < LDEPTH; ++d) sh.m.mk[col][sl * 16 + d] = tv[fc][d];
#pragma unroll
        for (int d = LDEPTH; d < 16; ++d) sh.m.mk[col][sl * 16 + d] = 0u;
    }
    __syncthreads();
    if (t < 128) {
        int p[4] = {0, 0, 0, 0};
        const size_t base = ((size_t)(qbase + t) * NSPLIT + split) * KEEP;
#pragma unroll 1
        for (int sel = 0; sel < KEEP; ++sel) {
            uint32 bk = 0; int bl = 0;
#pragma unroll
            for (int l = 0; l < 4; ++l) {
                uint32 k = sh.m.mk[t][l * 16 + p[l]];
                if (k > bk) { bk = k; bl = l; }
            }
            p[bl]++;
            keys_out[base + sel] = bk;
        }
    }
}

// ---------------- Phase C: one row per block — rank-select top-16 + fp64 rescue ----------------
__global__ __launch_bounds__(256) void rescue_kernel(
    const float* __restrict__ E, const double* __restrict__ invd,
    const uint32* __restrict__ keys,
    const int* __restrict__ n_users, const int* __restrict__ n_entitys,
    const int* __restrict__ interactions, float* __restrict__ out) {

    __shared__ uint32 skeys[128];
    __shared__ float4 sq[128];
    __shared__ int    scand[NRESC];
    __shared__ double sd[NRESC];
    __shared__ int    sci[NRESC];
    __shared__ float  smemb[NRESC];
    __shared__ double contrib[8];

    const int t   = threadIdx.x;
    const int row = blockIdx.x;

    if (t < 128) {
        skeys[t] = keys[(size_t)row * 128 + t];
        sq[t]    = ((const float4*)(E + (size_t)row * EMB))[t];
    }
    if (t < NRESC) scand[t] = 0;      // poison-proof
    if (t < 8)     contrib[t] = 0.0;
    __syncthreads();

    if (t < 128) {
        const uint32 k = skeys[t];
        int r = 0;
#pragma unroll 16
        for (int j = 0; j < 128; ++j) {
            const uint32 kj = skeys[j];
            r += (kj > k) || (kj == k && j < t);
        }
        if (r < NRESC) scand[r] = (int)((k & 0x1FFFu) ^ 0x1FFFu);
    }
    __syncthreads();

    const int g    = t >> 4;
    const int l16  = t & 15;
    const int cand = scand[g] & (NROWS - 1);
    const float4* C = (const float4*)(E + (size_t)cand * EMB);
    double acc = 0.0;
#pragma unroll
    for (int j = 0; j < 8; ++j) {
        float4 c = C[l16 + 16 * j];
        float4 q = sq[l16 + 16 * j];
        acc += (double)q.x * c.x + (double)q.y * c.y
             + (double)q.z * c.z + (double)q.w * c.w;
    }
#pragma unroll
    for (int m = 8; m >= 1; m >>= 1) acc += __shfl_xor(acc, m, 16);

    const int ent = n_entitys[row];
    if (l16 == 0) { sd[g] = acc * invd[row] * invd[cand]; sci[g] = cand; }
    if (l16 == 1) {
        const int uid = n_users[cand];
        smemb[g] = (float)interactions[(size_t)uid * NITEMS + ent];
    }
    __syncthreads();

    if (t < NRESC) {
        const double v  = sd[t];
        const int    ci = sci[t];
        int r = 0;
#pragma unroll
        for (int j = 0; j < NRESC; ++j) {
            const double vj = sd[j];
            const int    cj = sci[j];
            r += (vj > v) || (vj == v && (cj < ci || (cj == ci && j < t)));
        }
        if (r < 6) contrib[r] = v * (double)smemb[t];
    }
    __syncthreads();
    if (t == 0) {
        const double sum = contrib[0] + contrib[1] + contrib[2]
                         + contrib[3] + contrib[4] + contrib[5];
        out[row] = (float)(sum * (1.0 / 6.0));
    }
}

extern "C" void kernel_launch(void* const* d_in, const int* in_sizes, int n_in,
                              void* d_out, int out_size, void* d_ws, size_t ws_size,
                              hipStream_t stream) {
    const float* E            = (const float*)d_in[0];
    const int*   n_users      = (const int*)d_in[1];
    const int*   n_entitys    = (const int*)d_in[2];
    const int*   interactions = (const int*)d_in[3];
    float*       out          = (float*)d_out;

    uchar_t* Xq   = (uchar_t*)d_ws;
    double*  invd = (double*)(Xq + (size_t)NROWS * EMB);
    uint32*  keys = (uint32*)(invd + NROWS);

    prep_kernel<<<NROWS / 4, 256, 0, stream>>>(E, Xq, invd);
    sim_topk_mfma<<<(NROWS / QTILE) * NSPLIT, 256, 0, stream>>>(Xq, keys);
    rescue_kernel<<<NROWS, 256, 0, stream>>>(E, invd, keys, n_users, n_entitys,
                                             interactions, out);
}